// Round 6
// baseline (443.798 us; speedup 1.0000x reference)
//
#include <hip/hip_runtime.h>

// LengthRegulator, fully fused single kernel.
// x (32,1024,384) f32, duration (32,1024) i32, T=8192.
// out0: (32, 8192, 384) f32 gathered+masked;  out1: mel_len (32,) as f32.
//
// 8192 blocks x 256 thr (XCD-swizzled; each XCD streams one batch at a time
// -> x working set ~1.5MB, L2-resident). Each block:
//  1. int4-loads its batch's duration (4 KB, L2-broadcast), computes the full
//     csum in-register: local sum-of-4 + wave shuffle-scan + 4 wave totals in
//     LDS (2 barriers).
//  2. Run-intersection scatter: thread's 4 runs vs block window [t0,t0+32)
//     -> src[] in LDS (-1 = masked).
//  3. Streaming gather: 16B x-loads, regular 16B stores (fill evidence: no
//     RFO on full-line writes; regular store path reaches 6.3 TB/s).

#define BATCH 32
#define SRC_S 1024
#define DIM   384
#define ROWS  32          // output rows per block
#define C4    (DIM / 4)   // 96 16B-vectors per row
#define NXCD  8

typedef float f32x4 __attribute__((ext_vector_type(4)));
typedef int   i32x4 __attribute__((ext_vector_type(4)));

__global__ __launch_bounds__(256)
void lr_fused_kernel(const f32x4* __restrict__ x4,
                     const int* __restrict__ duration,
                     f32x4* __restrict__ out4,
                     float* __restrict__ mel_out, int T) {
    __shared__ int wsum[4];
    __shared__ int src[ROWS];

    const int l = blockIdx.x;              // 0 .. 8191
    const int xcd = l & (NXCD - 1);
    const int j = l >> 3;                  // 0 .. 1023
    const int b = xcd + NXCD * (j >> 8);   // one batch at a time per XCD
    const int t0 = (j & 255) * ROWS;       // 0 .. 8160
    const int tid = threadIdx.x;
    const int lane = tid & 63;
    const int wid = tid >> 6;              // 4 waves

    if (tid < ROWS) src[tid] = -1;         // default: masked (zero) row

    // ---- per-block csum of duration[b,:] ----
    const i32x4 d = ((const i32x4*)(duration + b * SRC_S))[tid];
    const int s0 = d.x;
    const int s1 = s0 + d.y;
    const int s2 = s1 + d.z;
    const int s3 = s2 + d.w;               // thread-local inclusive sums
    int tot = s3;
    #pragma unroll
    for (int off = 1; off < 64; off <<= 1) {   // wave inclusive scan
        const int n = __shfl_up(tot, off, 64);
        if (lane >= off) tot += n;
    }
    if (lane == 63) wsum[wid] = tot;
    __syncthreads();
    int base = 0;                          // sum of previous waves' totals
    #pragma unroll
    for (int w = 0; w < 3; ++w) base += (w < wid) ? wsum[w] : 0;
    const int mel_len = wsum[0] + wsum[1] + wsum[2] + wsum[3];
    const int pre = base + tot - s3;       // thread's exclusive prefix

    // ---- run-intersection scatter into src[] ----
    const int cs[4] = {pre + s0, pre + s1, pre + s2, pre + s3};  // run ends
    const int st[4] = {pre, pre + s0, pre + s1, pre + s2};       // run starts
    #pragma unroll
    for (int e = 0; e < 4; ++e) {
        const int lo = (st[e] > t0) ? st[e] : t0;
        const int hi = (cs[e] < t0 + ROWS) ? cs[e] : (t0 + ROWS);
        for (int t = lo; t < hi; ++t) src[t - t0] = tid * 4 + e;
    }
    __syncthreads();

    if (t0 == 0 && tid == 0) mel_out[b] = (float)mel_len;  // exact in f32

    // ---- streaming gather ----
    const f32x4* __restrict__ xb = x4 + (size_t)b * SRC_S * C4;
    f32x4* __restrict__ ob = out4 + ((size_t)b * T + t0) * C4;

    #pragma unroll
    for (int k = 0; k < (ROWS * C4) / 256; ++k) {   // 12 iterations
        const int i = tid + k * 256;
        const int row = i / C4;                      // const-div -> magic mul
        const int col = i - row * C4;
        const int sidx = src[row];                   // LDS broadcast
        f32x4 v = (f32x4)(0.f);
        if (sidx >= 0) v = xb[(size_t)sidx * C4 + col];
        ob[i] = v;                                   // regular (write-back) store
    }
}

extern "C" void kernel_launch(void* const* d_in, const int* in_sizes, int n_in,
                              void* d_out, int out_size, void* d_ws, size_t ws_size,
                              hipStream_t stream) {
    const float* x = (const float*)d_in[0];
    const int* duration = (const int*)d_in[1];
    const int T = (out_size - BATCH) / (BATCH * DIM);   // 8192

    float* out = (float*)d_out;
    float* mel_out = out + (size_t)BATCH * T * DIM;     // out1 region

    const int nblocks = BATCH * (T / ROWS);             // 8192
    lr_fused_kernel<<<nblocks, 256, 0, stream>>>((const f32x4*)x, duration,
                                                 (f32x4*)out, mel_out, T);
}

// Round 7
// 436.233 us; speedup vs baseline: 1.0173x; 1.0173x over previous
//
#include <hip/hip_runtime.h>

// LengthRegulator, fully fused single kernel.  (R5 configuration — best: 435.8us.
// R6 A/B showed non-temporal stores beat write-back by ~8us: streaming writes
// don't dirty L2, protecting the x gather working set.)
// x (32,1024,384) f32, duration (32,1024) i32, T=8192.
// out0: (32, 8192, 384) f32 gathered+masked;  out1: mel_len (32,) as f32.
//
// 8192 blocks x 256 thr (XCD-swizzled; each XCD streams one batch at a time
// -> x working set ~1.5MB, L2-resident). Each block:
//  1. int4-loads its batch's duration (4 KB, L2-broadcast), computes the full
//     csum in-register: local sum-of-4 + wave shuffle-scan + 4 wave totals in
//     LDS (2 barriers).
//  2. Run-intersection scatter: thread's 4 runs vs block window [t0,t0+32)
//     -> src[] in LDS (-1 = masked).
//  3. Streaming gather: 16B x-loads (L2-resident), non-temporal 16B stores.

#define BATCH 32
#define SRC_S 1024
#define DIM   384
#define ROWS  32          // output rows per block
#define C4    (DIM / 4)   // 96 16B-vectors per row
#define NXCD  8

typedef float f32x4 __attribute__((ext_vector_type(4)));
typedef int   i32x4 __attribute__((ext_vector_type(4)));

__global__ __launch_bounds__(256)
void lr_fused_kernel(const f32x4* __restrict__ x4,
                     const int* __restrict__ duration,
                     f32x4* __restrict__ out4,
                     float* __restrict__ mel_out, int T) {
    __shared__ int wsum[4];
    __shared__ int src[ROWS];

    const int l = blockIdx.x;              // 0 .. 8191
    const int xcd = l & (NXCD - 1);
    const int j = l >> 3;                  // 0 .. 1023
    const int b = xcd + NXCD * (j >> 8);   // one batch at a time per XCD
    const int t0 = (j & 255) * ROWS;       // 0 .. 8160
    const int tid = threadIdx.x;
    const int lane = tid & 63;
    const int wid = tid >> 6;              // 4 waves

    if (tid < ROWS) src[tid] = -1;         // default: masked (zero) row

    // ---- per-block csum of duration[b,:] ----
    const i32x4 d = ((const i32x4*)(duration + b * SRC_S))[tid];
    const int s0 = d.x;
    const int s1 = s0 + d.y;
    const int s2 = s1 + d.z;
    const int s3 = s2 + d.w;               // thread-local inclusive sums
    int tot = s3;
    #pragma unroll
    for (int off = 1; off < 64; off <<= 1) {   // wave inclusive scan
        const int n = __shfl_up(tot, off, 64);
        if (lane >= off) tot += n;
    }
    if (lane == 63) wsum[wid] = tot;
    __syncthreads();
    int base = 0;                          // sum of previous waves' totals
    #pragma unroll
    for (int w = 0; w < 3; ++w) base += (w < wid) ? wsum[w] : 0;
    const int mel_len = wsum[0] + wsum[1] + wsum[2] + wsum[3];
    const int pre = base + tot - s3;       // thread's exclusive prefix

    // ---- run-intersection scatter into src[] ----
    const int cs[4] = {pre + s0, pre + s1, pre + s2, pre + s3};  // run ends
    const int st[4] = {pre, pre + s0, pre + s1, pre + s2};       // run starts
    #pragma unroll
    for (int e = 0; e < 4; ++e) {
        const int lo = (st[e] > t0) ? st[e] : t0;
        const int hi = (cs[e] < t0 + ROWS) ? cs[e] : (t0 + ROWS);
        for (int t = lo; t < hi; ++t) src[t - t0] = tid * 4 + e;
    }
    __syncthreads();

    if (t0 == 0 && tid == 0) mel_out[b] = (float)mel_len;  // exact in f32

    // ---- streaming gather ----
    const f32x4* __restrict__ xb = x4 + (size_t)b * SRC_S * C4;
    f32x4* __restrict__ ob = out4 + ((size_t)b * T + t0) * C4;

    #pragma unroll
    for (int k = 0; k < (ROWS * C4) / 256; ++k) {   // 12 iterations
        const int i = tid + k * 256;
        const int row = i / C4;                      // const-div -> magic mul
        const int col = i - row * C4;
        const int sidx = src[row];                   // LDS broadcast
        f32x4 v = (f32x4)(0.f);
        if (sidx >= 0) v = xb[(size_t)sidx * C4 + col];
        __builtin_nontemporal_store(v, &ob[i]);      // streaming out (R6: beats write-back)
    }
}

extern "C" void kernel_launch(void* const* d_in, const int* in_sizes, int n_in,
                              void* d_out, int out_size, void* d_ws, size_t ws_size,
                              hipStream_t stream) {
    const float* x = (const float*)d_in[0];
    const int* duration = (const int*)d_in[1];
    const int T = (out_size - BATCH) / (BATCH * DIM);   // 8192

    float* out = (float*)d_out;
    float* mel_out = out + (size_t)BATCH * T * DIM;     // out1 region

    const int nblocks = BATCH * (T / ROWS);             // 8192
    lr_fused_kernel<<<nblocks, 256, 0, stream>>>((const f32x4*)x, duration,
                                                 (f32x4*)out, mel_out, T);
}